// Round 6
// baseline (437.254 us; speedup 1.0000x reference)
//
#include <hip/hip_runtime.h>
#include <cstddef>

#define SQLEN 2048
#define DMODEL 2048
#define NHEADS 16
#define DHEAD 128

typedef __attribute__((ext_vector_type(8))) short bf16x8;
typedef __attribute__((ext_vector_type(4))) float floatx4;

__device__ __forceinline__ unsigned short f2bf(float f) {
  union { float f; unsigned u; } c; c.f = f;
  unsigned u = c.u;
  unsigned r = u + 0x7fffu + ((u >> 16) & 1u);
  return (unsigned short)(r >> 16);
}
__device__ __forceinline__ float bf2f(unsigned short s) {
  union { unsigned u; float f; } c; c.u = ((unsigned)s) << 16;
  return c.f;
}

// ---------------- fp32 -> bf16 convert (vectorized) -------------------------
__global__ __launch_bounds__(256) void f2b_kernel(const float4* __restrict__ in,
                                                  ushort4* __restrict__ out) {
  int i = blockIdx.x * 256 + threadIdx.x;
  float4 v = in[i];
  ushort4 o;
  o.x = f2bf(v.x); o.y = f2bf(v.y); o.z = f2bf(v.z); o.w = f2bf(v.w);
  out[i] = o;
}

// two-array variant (W_gate, W_out in one launch)
__global__ __launch_bounds__(256) void f2b2_kernel(const float4* __restrict__ in0,
                                                   ushort4* __restrict__ out0,
                                                   const float4* __restrict__ in1,
                                                   ushort4* __restrict__ out1,
                                                   int half_blocks) {
  int b = blockIdx.x;
  const float4* in = (b < half_blocks) ? in0 : in1;
  ushort4* out = (b < half_blocks) ? out0 : out1;
  int i = (b < half_blocks ? b : b - half_blocks) * 256 + threadIdx.x;
  float4 v = in[i];
  ushort4 o;
  o.x = f2bf(v.x); o.y = f2bf(v.y); o.z = f2bf(v.z); o.w = f2bf(v.w);
  out[i] = o;
}

// --- W_qkv convert with xpos-pair row permutation (q,k parts only) ----------
// Output row pos within a 128-row head block holds source j:
//   p64 = pos&63; j = (pos>>6)*32 + (p64<32 ? p64 : p64-32+64)
// so reg cols jt and jt+2 in the GEMM C-tile are rotation partners.
__global__ __launch_bounds__(256) void f2bperm_kernel(const float* __restrict__ in,
                                                      unsigned short* __restrict__ out) {
  int idx = blockIdx.x * 256 + threadIdx.x;  // over 6144*512 float4
  int n = idx >> 9, c4 = idx & 511;
  int src;
  if (n < 4096) {
    int posh = n & 127;
    int half = posh >> 6, p64 = posh & 63;
    int j = (p64 < 32) ? (half * 32 + p64) : (half * 32 + p64 - 32 + 64);
    src = (n & ~127) + j;
  } else {
    src = n;
  }
  float4 v = *(const float4*)(in + (size_t)src * DMODEL + c4 * 4);
  ushort4 o;
  o.x = f2bf(v.x); o.y = f2bf(v.y); o.z = f2bf(v.z); o.w = f2bf(v.w);
  *(ushort4*)(out + (size_t)n * DMODEL + c4 * 4) = o;
}

// swizzled LDS chunk position: 2-way-max bank aliasing for b128 frag reads
#define SWZ(r, q) ((q) ^ (((r) >> 1) & 3))

// ---------------- qkv GEMM with fused xpos epilogue -------------------------
// C-tile (128 rows t, 128 cols) = one head of one of q/k/v (B rows permuted).
__global__ __launch_bounds__(256) void gemm_qkv_xpos(const unsigned short* __restrict__ A,
                                                     const unsigned short* __restrict__ B,
                                                     const float* __restrict__ a_raw,
                                                     const int* __restrict__ offset_p,
                                                     unsigned short* __restrict__ qb,
                                                     unsigned short* __restrict__ kb,
                                                     unsigned short* __restrict__ vb) {
  __shared__ __align__(16) unsigned short As[128 * 32];
  __shared__ __align__(16) unsigned short Bs[128 * 32];
  const int K = 2048;
  int tid = threadIdx.x;
  int wave = tid >> 6, lane = tid & 63;
  int wm = wave >> 1, wn = wave & 1;
  int quad = lane >> 4, m16 = lane & 15;
  int row0 = blockIdx.y * 128, col0 = blockIdx.x * 128;

  floatx4 acc[4][4];
#pragma unroll
  for (int i = 0; i < 4; i++)
#pragma unroll
    for (int j = 0; j < 4; j++) acc[i][j] = (floatx4){0.f, 0.f, 0.f, 0.f};

  int c0 = tid, c1 = tid + 256;
  int r0c = c0 >> 2, p0c = c0 & 3;
  int r1c = c1 >> 2, p1c = c1 & 3;
  int q0c = SWZ(r0c, p0c) * 8, q1c = SWZ(r1c, p1c) * 8;

  for (int k0 = 0; k0 < K; k0 += 32) {
    __builtin_amdgcn_global_load_lds(
        (const __attribute__((address_space(1))) unsigned int*)(A + (size_t)(row0 + r0c) * K + k0 + q0c),
        (__attribute__((address_space(3))) unsigned int*)(As + c0 * 8), 16, 0, 0);
    __builtin_amdgcn_global_load_lds(
        (const __attribute__((address_space(1))) unsigned int*)(A + (size_t)(row0 + r1c) * K + k0 + q1c),
        (__attribute__((address_space(3))) unsigned int*)(As + c1 * 8), 16, 0, 0);
    __builtin_amdgcn_global_load_lds(
        (const __attribute__((address_space(1))) unsigned int*)(B + (size_t)(col0 + r0c) * K + k0 + q0c),
        (__attribute__((address_space(3))) unsigned int*)(Bs + c0 * 8), 16, 0, 0);
    __builtin_amdgcn_global_load_lds(
        (const __attribute__((address_space(1))) unsigned int*)(B + (size_t)(col0 + r1c) * K + k0 + q1c),
        (__attribute__((address_space(3))) unsigned int*)(Bs + c1 * 8), 16, 0, 0);
    __syncthreads();

    bf16x8 af[4], bfr[4];
#pragma unroll
    for (int i = 0; i < 4; i++) {
      int rr = wm * 64 + i * 16 + m16;
      af[i] = *(const bf16x8*)(As + rr * 32 + SWZ(rr, quad) * 8);
    }
#pragma unroll
    for (int j = 0; j < 4; j++) {
      int rr = wn * 64 + j * 16 + m16;
      bfr[j] = *(const bf16x8*)(Bs + rr * 32 + SWZ(rr, quad) * 8);
    }
#pragma unroll
    for (int i = 0; i < 4; i++)
#pragma unroll
      for (int j = 0; j < 4; j++)
        acc[i][j] = __builtin_amdgcn_mfma_f32_16x16x32_bf16(af[i], bfr[j], acc[i][j], 0, 0, 0);
    __syncthreads();
  }

  int part = col0 >> 11;          // 0=q, 1=k, 2=v
  int h = (col0 & 2047) >> 7;
  int off = offset_p[0];

  if (part == 2) {
#pragma unroll
    for (int i = 0; i < 4; i++)
#pragma unroll
      for (int jt = 0; jt < 4; jt++) {
        int d = wn * 64 + jt * 16 + m16;
#pragma unroll
        for (int r = 0; r < 4; r++) {
          int t = row0 + wm * 64 + i * 16 + quad * 4 + r;
          vb[((size_t)h * SQLEN + t) * DHEAD + d] = f2bf(acc[i][jt][r]);
        }
      }
  } else {
    unsigned short* dst = part ? kb : qb;
#pragma unroll
    for (int jt = 0; jt < 2; jt++) {
      int j = wn * 32 + jt * 16 + m16;
      float freq = exp2f(-(float)j * (13.287712379549449f / 64.f));
      float lz = __log2f((2.f * (float)j + 51.2f) / 179.2f);
#pragma unroll
      for (int i = 0; i < 4; i++) {
#pragma unroll
        for (int r = 0; r < 4; r++) {
          int t = row0 + wm * 64 + i * 16 + quad * 4 + r;
          float pos = (float)(t + off);
          float ang = pos * freq;
          float sn = __sinf(ang), cs = __cosf(ang);
          float lzp = lz * pos * (1.f / 512.f);
          float scl;
          if (part == 0) scl = exp2f(lzp);
          else scl = (1.f - __expf(a_raw[(size_t)h * SQLEN + t])) * exp2f(-lzp);
          float x1 = acc[i][jt][r], x2 = acc[i][jt + 2][r];
          size_t o = ((size_t)h * SQLEN + t) * DHEAD + j;
          dst[o] = f2bf((x1 * cs - x2 * sn) * scl);
          dst[o + 64] = f2bf((x2 * cs + x1 * sn) * scl);
        }
      }
    }
  }
}

// ---------------- bf16 MFMA GEMM: C[M,N] = A[M,K] @ B[N,K]^T ----------------
__global__ __launch_bounds__(256) void gemm_bf16_nt(const unsigned short* __restrict__ A,
                                                    const unsigned short* __restrict__ B,
                                                    float* __restrict__ C,
                                                    int M, int N, int K) {
  __shared__ __align__(16) unsigned short As[128 * 32];
  __shared__ __align__(16) unsigned short Bs[128 * 32];
  int tid = threadIdx.x;
  int wave = tid >> 6, lane = tid & 63;
  int wm = wave >> 1, wn = wave & 1;
  int quad = lane >> 4, m16 = lane & 15;
  int row0 = blockIdx.y * 128, col0 = blockIdx.x * 128;

  floatx4 acc[4][4];
#pragma unroll
  for (int i = 0; i < 4; i++)
#pragma unroll
    for (int j = 0; j < 4; j++) acc[i][j] = (floatx4){0.f, 0.f, 0.f, 0.f};

  int c0 = tid, c1 = tid + 256;
  int r0c = c0 >> 2, q0c = SWZ(r0c, c0 & 3) * 8;
  int r1c = c1 >> 2, q1c = SWZ(r1c, c1 & 3) * 8;

  const size_t sK = (size_t)K;
  for (int k0 = 0; k0 < K; k0 += 32) {
    __builtin_amdgcn_global_load_lds(
        (const __attribute__((address_space(1))) unsigned int*)(A + (size_t)(row0 + r0c) * sK + k0 + q0c),
        (__attribute__((address_space(3))) unsigned int*)(As + c0 * 8), 16, 0, 0);
    __builtin_amdgcn_global_load_lds(
        (const __attribute__((address_space(1))) unsigned int*)(A + (size_t)(row0 + r1c) * sK + k0 + q1c),
        (__attribute__((address_space(3))) unsigned int*)(As + c1 * 8), 16, 0, 0);
    __builtin_amdgcn_global_load_lds(
        (const __attribute__((address_space(1))) unsigned int*)(B + (size_t)(col0 + r0c) * sK + k0 + q0c),
        (__attribute__((address_space(3))) unsigned int*)(Bs + c0 * 8), 16, 0, 0);
    __builtin_amdgcn_global_load_lds(
        (const __attribute__((address_space(1))) unsigned int*)(B + (size_t)(col0 + r1c) * sK + k0 + q1c),
        (__attribute__((address_space(3))) unsigned int*)(Bs + c1 * 8), 16, 0, 0);
    __syncthreads();

    bf16x8 af[4], bfr[4];
#pragma unroll
    for (int i = 0; i < 4; i++) {
      int rr = wm * 64 + i * 16 + m16;
      af[i] = *(const bf16x8*)(As + rr * 32 + SWZ(rr, quad) * 8);
    }
#pragma unroll
    for (int j = 0; j < 4; j++) {
      int rr = wn * 64 + j * 16 + m16;
      bfr[j] = *(const bf16x8*)(Bs + rr * 32 + SWZ(rr, quad) * 8);
    }
#pragma unroll
    for (int i = 0; i < 4; i++)
#pragma unroll
      for (int j = 0; j < 4; j++)
        acc[i][j] = __builtin_amdgcn_mfma_f32_16x16x32_bf16(af[i], bfr[j], acc[i][j], 0, 0, 0);
    __syncthreads();
  }

#pragma unroll
  for (int i = 0; i < 4; i++) {
#pragma unroll
    for (int j = 0; j < 4; j++) {
      int rr = row0 + wm * 64 + i * 16 + quad * 4;
      int cc = col0 + wn * 64 + j * 16 + m16;
#pragma unroll
      for (int r = 0; r < 4; r++)
        C[(size_t)(rr + r) * N + cc] = acc[i][j][r];
    }
  }
}

// ------- gate GEMM with fused swish*rn epilogue, bf16 output ---------------
__global__ __launch_bounds__(256) void gemm_swish_nt(const unsigned short* __restrict__ A,
                                                     const unsigned short* __restrict__ B,
                                                     const float* __restrict__ rn,
                                                     unsigned short* __restrict__ Hb,
                                                     int M, int N, int K) {
  __shared__ __align__(16) unsigned short As[128 * 32];
  __shared__ __align__(16) unsigned short Bs[128 * 32];
  int tid = threadIdx.x;
  int wave = tid >> 6, lane = tid & 63;
  int wm = wave >> 1, wn = wave & 1;
  int quad = lane >> 4, m16 = lane & 15;
  int row0 = blockIdx.y * 128, col0 = blockIdx.x * 128;

  floatx4 acc[4][4];
#pragma unroll
  for (int i = 0; i < 4; i++)
#pragma unroll
    for (int j = 0; j < 4; j++) acc[i][j] = (floatx4){0.f, 0.f, 0.f, 0.f};

  int c0 = tid, c1 = tid + 256;
  int r0c = c0 >> 2, q0c = SWZ(r0c, c0 & 3) * 8;
  int r1c = c1 >> 2, q1c = SWZ(r1c, c1 & 3) * 8;

  const size_t sK = (size_t)K;
  for (int k0 = 0; k0 < K; k0 += 32) {
    __builtin_amdgcn_global_load_lds(
        (const __attribute__((address_space(1))) unsigned int*)(A + (size_t)(row0 + r0c) * sK + k0 + q0c),
        (__attribute__((address_space(3))) unsigned int*)(As + c0 * 8), 16, 0, 0);
    __builtin_amdgcn_global_load_lds(
        (const __attribute__((address_space(1))) unsigned int*)(A + (size_t)(row0 + r1c) * sK + k0 + q1c),
        (__attribute__((address_space(3))) unsigned int*)(As + c1 * 8), 16, 0, 0);
    __builtin_amdgcn_global_load_lds(
        (const __attribute__((address_space(1))) unsigned int*)(B + (size_t)(col0 + r0c) * sK + k0 + q0c),
        (__attribute__((address_space(3))) unsigned int*)(Bs + c0 * 8), 16, 0, 0);
    __builtin_amdgcn_global_load_lds(
        (const __attribute__((address_space(1))) unsigned int*)(B + (size_t)(col0 + r1c) * sK + k0 + q1c),
        (__attribute__((address_space(3))) unsigned int*)(Bs + c1 * 8), 16, 0, 0);
    __syncthreads();

    bf16x8 af[4], bfr[4];
#pragma unroll
    for (int i = 0; i < 4; i++) {
      int rr = wm * 64 + i * 16 + m16;
      af[i] = *(const bf16x8*)(As + rr * 32 + SWZ(rr, quad) * 8);
    }
#pragma unroll
    for (int j = 0; j < 4; j++) {
      int rr = wn * 64 + j * 16 + m16;
      bfr[j] = *(const bf16x8*)(Bs + rr * 32 + SWZ(rr, quad) * 8);
    }
#pragma unroll
    for (int i = 0; i < 4; i++)
#pragma unroll
      for (int j = 0; j < 4; j++)
        acc[i][j] = __builtin_amdgcn_mfma_f32_16x16x32_bf16(af[i], bfr[j], acc[i][j], 0, 0, 0);
    __syncthreads();
  }

#pragma unroll
  for (int i = 0; i < 4; i++) {
#pragma unroll
    for (int j = 0; j < 4; j++) {
      int rr = row0 + wm * 64 + i * 16 + quad * 4;
      int cc = col0 + wn * 64 + j * 16 + m16;
#pragma unroll
      for (int r = 0; r < 4; r++) {
        float g = acc[i][j][r];
        float rv = rn[(size_t)(rr + r) * N + cc];
        float hh = g / (1.f + __expf(-g)) * rv;
        Hb[(size_t)(rr + r) * N + cc] = f2bf(hh);
      }
    }
  }
}

// ---------------- alpha: block = 4 t-rows staged in LDS, loop 16 heads ------
__global__ __launch_bounds__(256) void alpha_kernel(const float* __restrict__ x,
                                                    const float* __restrict__ W_alpha,
                                                    const float* __restrict__ b_alpha,
                                                    const float* __restrict__ alpha_base,
                                                    float* __restrict__ a_raw) {
  __shared__ float xs[4][2048];
  int tid = threadIdx.x;
  int t0 = blockIdx.x * 4;
#pragma unroll
  for (int p = 0; p < 8; p++) {
    int idx = tid + p * 256;
    int row = idx >> 9, c4 = idx & 511;
    *(float4*)&xs[row][c4 * 4] = *(const float4*)(x + (size_t)(t0 + row) * DMODEL + c4 * 4);
  }
  __syncthreads();
  int w = tid >> 6, lane = tid & 63;
  int t = t0 + w;
#pragma unroll
  for (int h = 0; h < NHEADS; h++) {
    const float4* wr = (const float4*)(W_alpha + (size_t)h * DMODEL);
    float s = 0.f;
#pragma unroll
    for (int i = lane; i < 512; i += 64) {
      float4 a = *(const float4*)&xs[w][i * 4];
      float4 b = wr[i];
      s += a.x * b.x + a.y * b.y + a.z * b.z + a.w * b.w;
    }
#pragma unroll
    for (int off = 32; off > 0; off >>= 1) s += __shfl_down(s, off);
    if (lane == 0) {
      float sig = 1.f / (1.f + __expf(-(s + b_alpha[h])));
      a_raw[(size_t)h * SQLEN + t] = alpha_base[h] * 8.f * sig;
    }
  }
}

// ---------------- cumsum ----------------------------------------------------
__global__ __launch_bounds__(256) void cumsum_kernel(const float* __restrict__ a_raw,
                                                     float* __restrict__ A) {
  int h = blockIdx.x;
  __shared__ float part[256];
  int tid = threadIdx.x;
  float v[8];
  float s = 0.f;
#pragma unroll
  for (int i = 0; i < 8; i++) {
    v[i] = a_raw[(size_t)h * SQLEN + tid * 8 + i];
    s += v[i];
  }
  part[tid] = s;
  __syncthreads();
  for (int off = 1; off < 256; off <<= 1) {
    float tmp = (tid >= off) ? part[tid - off] : 0.f;
    __syncthreads();
    part[tid] += tmp;
    __syncthreads();
  }
  float run = (tid > 0) ? part[tid - 1] : 0.f;
#pragma unroll
  for (int i = 0; i < 8; i++) {
    run += v[i];
    A[(size_t)h * SQLEN + tid * 8 + i] = run;
  }
}

// ------- transpose kb/vb [h][t][d] -> [h][d][t]; k gets exp(B-A[t]) scale ---
__global__ __launch_bounds__(256) void transpose_kv_kernel(const unsigned short* __restrict__ kb,
                                                           const unsigned short* __restrict__ vb,
                                                           const float* __restrict__ A,
                                                           unsigned short* __restrict__ kT,
                                                           unsigned short* __restrict__ vT) {
  __shared__ __align__(16) unsigned short tile[64][72];
  int h = blockIdx.z >> 1, sel = blockIdx.z & 1;
  int t0 = blockIdx.x * 64, d0 = blockIdx.y * 64;
  int tid = threadIdx.x;
  const unsigned short* src = (sel ? vb : kb) + ((size_t)h * SQLEN + t0) * DHEAD + d0;
  unsigned short* dst = (sel ? vT : kT) + (size_t)h * (DHEAD * SQLEN) + (size_t)d0 * SQLEN + t0;
  float B = A[(size_t)h * SQLEN + SQLEN - 1];
#pragma unroll
  for (int p = 0; p < 2; p++) {
    int c = tid + p * 256;
    int r = c >> 3, off = (c & 7) * 8;
    bf16x8 in = *(const bf16x8*)(src + (size_t)r * DHEAD + off);
    if (!sel) {
      float w = __expf(B - A[(size_t)h * SQLEN + t0 + r]);
      bf16x8 o;
#pragma unroll
      for (int j = 0; j < 8; j++) o[j] = (short)f2bf(bf2f((unsigned short)in[j]) * w);
      *(bf16x8*)&tile[r][off] = o;
    } else {
      *(bf16x8*)&tile[r][off] = in;
    }
  }
  __syncthreads();
#pragma unroll
  for (int p = 0; p < 2; p++) {
    int c = tid + p * 256;
    int dr = c >> 3, toff = (c & 7) * 8;
    bf16x8 o;
#pragma unroll
    for (int j = 0; j < 8; j++) o[j] = (short)tile[toff + j][dr];
    *(bf16x8*)(dst + (size_t)dr * SQLEN + toff) = o;
  }
}

// ---------------- transpose state -> stT bf16 [h][e][d] ---------------------
__global__ __launch_bounds__(256) void transpose_state_kernel(const float* __restrict__ st,
                                                              unsigned short* __restrict__ stT) {
  __shared__ float tile[64][65];
  int h = blockIdx.z, d0 = blockIdx.x * 64, e0 = blockIdx.y * 64;
  int tid = threadIdx.x;
  const float* src = st + (size_t)h * 16384 + (size_t)d0 * DHEAD + e0;
#pragma unroll
  for (int p = 0; p < 4; p++) {
    int idx = tid + p * 256;
    int r = idx >> 4, c = (idx & 15) * 4;
    float4 f = *(const float4*)(src + (size_t)r * DHEAD + c);
    tile[r][c] = f.x; tile[r][c + 1] = f.y; tile[r][c + 2] = f.z; tile[r][c + 3] = f.w;
  }
  __syncthreads();
  unsigned short* dst = stT + (size_t)h * 16384 + (size_t)e0 * DHEAD + d0;
#pragma unroll
  for (int p = 0; p < 2; p++) {
    int idx = tid + p * 256;
    int er = idx >> 3, doff = (idx & 7) * 8;
    bf16x8 o;
#pragma unroll
    for (int j = 0; j < 8; j++) o[j] = (short)f2bf(tile[doff + j][er]);
    *(bf16x8*)(dst + (size_t)er * DHEAD + doff) = o;
  }
}

// ---------------- retention: MFMA + fused group-norm epilogue ---------------
__global__ __launch_bounds__(256) void retention_mfma(const unsigned short* __restrict__ qb,
                                                      const unsigned short* __restrict__ kb,
                                                      const unsigned short* __restrict__ vT,
                                                      const unsigned short* __restrict__ stT,
                                                      const float* __restrict__ A,
                                                      const float* __restrict__ gn_w,
                                                      const float* __restrict__ gn_b,
                                                      float* __restrict__ rn,
                                                      unsigned short* __restrict__ rnb) {
  __shared__ __align__(16) unsigned short ks[64 * 128];
  __shared__ __align__(16) unsigned short vs[128 * 64];
  __shared__ __align__(16) unsigned short Ss[64 * 72];
  __shared__ float djs[64];
  int h = blockIdx.x;
  int i0 = blockIdx.y * 64;
  int tid = threadIdx.x;
  int wave = tid >> 6, lane = tid & 63, quad = lane >> 4, m16 = lane & 15;
  const float* Ah = A + (size_t)h * SQLEN;
  float c = Ah[i0];
  int rq = wave * 16 + m16;

  const unsigned short* qh = qb + ((size_t)h * SQLEN + i0 + rq) * DHEAD;
  bf16x8 qf[4];
#pragma unroll
  for (int dc = 0; dc < 4; dc++)
    qf[dc] = *(const bf16x8*)(qh + dc * 32 + quad * 8);
  float ei = __expf(Ah[i0 + rq] - c);

  float wg[8], bg[8];
#pragma unroll
  for (int et = 0; et < 8; et++) {
    int col = h * DHEAD + et * 16 + m16;
    wg[et] = gn_w[col];
    bg[et] = gn_b[col];
  }

  floatx4 acc[8];
#pragma unroll
  for (int et = 0; et < 8; et++) acc[et] = (floatx4){0.f, 0.f, 0.f, 0.f};

  if (c > -87.f) {
    const unsigned short* sp = stT + (size_t)h * 16384;
    float ecr[4];
#pragma unroll
    for (int r = 0; r < 4; r++) ecr[r] = __expf(Ah[i0 + wave * 16 + quad * 4 + r]);
#pragma unroll
    for (int et = 0; et < 8; et++) {
#pragma unroll
      for (int dc = 0; dc < 4; dc++) {
        bf16x8 sf = *(const bf16x8*)(sp + (et * 16 + m16) * DHEAD + dc * 32 + quad * 8);
        acc[et] = __builtin_amdgcn_mfma_f32_16x16x32_bf16(qf[dc], sf, acc[et], 0, 0, 0);
      }
#pragma unroll
      for (int r = 0; r < 4; r++) acc[et][r] *= ecr[r];
    }
  }

  for (int j0 = 0; j0 <= i0; j0 += 64) {
    if (c - Ah[j0 + 63] < -87.f) continue;
    __syncthreads();
    const unsigned short* kh = kb + ((size_t)h * SQLEN + j0) * DHEAD;
    const unsigned short* vh = vT + (size_t)h * (DHEAD * SQLEN) + j0;
#pragma unroll
    for (int p = 0; p < 4; p++) {
      int cch = tid + p * 256;
      int r = cch >> 4, kp = (cch & 15) ^ (r & 7);
      __builtin_amdgcn_global_load_lds(
          (const __attribute__((address_space(1))) unsigned int*)(kh + (size_t)r * DHEAD + kp * 8),
          (__attribute__((address_space(3))) unsigned int*)(ks + cch * 8), 16, 0, 0);
      int e = cch >> 3, tp = (cch & 7) ^ (e & 7);
      __builtin_amdgcn_global_load_lds(
          (const __attribute__((address_space(1))) unsigned int*)(vh + (size_t)e * SQLEN + tp * 8),
          (__attribute__((address_space(3))) unsigned int*)(vs + cch * 8), 16, 0, 0);
    }
    if (tid < 64) djs[tid] = __expf(c - Ah[j0 + tid]);
    __syncthreads();

    bool diag = (j0 == i0);
#pragma unroll
    for (int jt = 0; jt < 4; jt++) {
      floatx4 s = (floatx4){0.f, 0.f, 0.f, 0.f};
#pragma unroll
      for (int dc = 0; dc < 4; dc++) {
        int rk = jt * 16 + m16;
        bf16x8 kf = *(const bf16x8*)(ks + rk * 128 + (((dc * 4 + quad) ^ (rk & 7)) * 8));
        s = __builtin_amdgcn_mfma_f32_16x16x32_bf16(kf, qf[dc], s, 0, 0, 0);
      }
      int jb = jt * 16 + quad * 4;
      float4 dj4 = *(const float4*)&djs[jb];
      ushort4 pk;
      pk.x = f2bf((diag && (jb + 0 > rq)) ? 0.f : s[0] * ei * dj4.x);
      pk.y = f2bf((diag && (jb + 1 > rq)) ? 0.f : s[1] * ei * dj4.y);
      pk.z = f2bf((diag && (jb + 2 > rq)) ? 0.f : s[2] * ei * dj4.z);
      pk.w = f2bf((diag && (jb + 3 > rq)) ? 0.f : s[3] * ei * dj4.w);
      *(ushort4*)(Ss + rq * 72 + jb) = pk;
    }

    bf16x8 sfr[2];
#pragma unroll
    for (int kc = 0; kc < 2; kc++)
      sfr[kc] = *(const bf16x8*)(Ss + rq * 72 + kc * 32 + quad * 8);
#pragma unroll
    for (int et = 0; et < 8; et++) {
#pragma unroll
      for (int kc = 0; kc < 2; kc++) {
        int e = et * 16 + m16;
        bf16x8 vf = *(const bf16x8*)(vs + e * 64 + (((kc * 4 + quad) ^ (e & 7)) * 8));
        acc[et] = __builtin_amdgcn_mfma_f32_16x16x32_bf16(sfr[kc], vf, acc[et], 0, 0, 0);
      }
    }
  }

#pragma unroll
  for (int r = 0; r < 4; r++) {
    float s = 0.f, ss = 0.f;
#pragma unroll
    for (int et = 0; et < 8; et++) {
      float v = acc[et][r];
      s += v; ss += v * v;
    }
#pragma unroll
    for (int off = 8; off > 0; off >>= 1) {
      s += __shfl_xor(s, off);
      ss += __shfl_xor(ss, off);
    }
    float mu = s * (1.f / 128.f);
    float var = ss * (1.f / 128.f) - mu * mu;
    float inv = rsqrtf(var + 1e-5f);
    int row = i0 + wave * 16 + quad * 4 + r;
    size_t o = (size_t)row * DMODEL + h * DHEAD;
#pragma unroll
    for (int et = 0; et < 8; et++) {
      float rv = (acc[et][r] - mu) * inv * wg[et] + bg[et];
      rn[o + et * 16 + m16] = rv;
      rnb[o + et * 16 + m16] = f2bf(rv);
    }
  }
}

// -------- new_state GEMM: P[h,chunk] = kT_s[:,krange] @ vT[:,krange]^T ------
__global__ __launch_bounds__(256) void state_gemm(const unsigned short* __restrict__ kT,
                                                  const unsigned short* __restrict__ vT,
                                                  float* __restrict__ P) {
  __shared__ __align__(16) unsigned short As[128 * 32];
  __shared__ __align__(16) unsigned short Bs[128 * 32];
  int chunk = blockIdx.x, h = blockIdx.y;
  int tid = threadIdx.x;
  int wave = tid >> 6, lane = tid & 63;
  int wm = wave >> 1, wn = wave & 1;
  int quad = lane >> 4, m16 = lane & 15;
  const unsigned short* Ab = kT + (size_t)h * (DHEAD * SQLEN);
  const unsigned short* Bb = vT + (size_t)h * (DHEAD * SQLEN);

  floatx4 acc[4][4];
#pragma unroll
  for (int i = 0; i < 4; i++)
#pragma unroll
    for (int j = 0; j < 4; j++) acc[i][j] = (floatx4){0.f, 0.f, 0.f, 0.f};

  int c0 = tid, c1 = tid + 256;
  int r0c = c0 >> 2, q0c = SWZ(r0c, c0 & 3) * 8;
  int r1c = c1 >> 2, q1c = SWZ(r1c, c1 & 3) * 8;

  for (int k0 = chunk * 256; k0 < chunk * 256 + 256; k0 += 32) {
    __builtin_amdgcn_global_load_lds(
        (const __attribute__((address_space(1))) unsigned int*)(Ab + (size_t)r0c * SQLEN + k0 + q0c),
        (__attribute__((address_space(3))) unsigned int*)(As + c0 * 8), 16, 0, 0);
    __builtin_amdgcn_global_load_lds(
        (const __attribute__((address_space(1))) unsigned int*)(Ab + (size_t)r1c * SQLEN + k0 + q1c),
        (__attribute__((address_space(3))) unsigned int*)(As + c1 * 8), 16, 0, 0);
    __builtin_amdgcn_global_load_lds(
        (const __attribute__((address_space(1))) unsigned int*)(Bb + (size_t)r0c * SQLEN + k0 + q0c),
        (__attribute__((address_space(3))) unsigned int*)(Bs + c0 * 8), 16, 0, 0);
    __builtin_amdgcn_global_load_lds(
        (const __attribute__((address_space(1))) unsigned int*)(Bb + (size_t)r1c * SQLEN + k0 + q1c),
        (__attribute__((address_space(3))) unsigned int*)(Bs + c1 * 8), 16, 0, 0);
    __syncthreads();

    bf16x8 af[4], bfr[4];
#pragma unroll
    for (int i = 0; i < 4; i++) {
      int rr = wm * 64 + i * 16 + m16;
      af[i] = *(const bf16x8*)(As + rr * 32 + SWZ(rr, quad) * 8);
    }
#pragma unroll
    for (int j = 0; j < 4; j++) {
      int rr = wn * 64 + j * 16 + m16;
      bfr[j] = *(const bf16x8*)(Bs + rr * 32 + SWZ(rr, quad) * 8);
    }
#pragma unroll
    for (int i = 0; i < 4; i++)
#pragma unroll
      for (int j = 0; j < 4; j++)
        acc[i][j] = __builtin_amdgcn_mfma_f32_16x16x32_bf16(af[i], bfr[j], acc[i][j], 0, 0, 0);
    __syncthreads();
  }

  float* Pp = P + (size_t)(h * 8 + chunk) * 16384;
#pragma unroll
  for (int i = 0; i < 4; i++)
#pragma unroll
    for (int j = 0; j < 4; j++) {
      int rr = wm * 64 + i * 16 + quad * 4;
      int cc = wn * 64 + j * 16 + m16;
#pragma unroll
      for (int r = 0; r < 4; r++)
        Pp[(size_t)(rr + r) * DHEAD + cc] = acc[i][j][r];
    }
}

__global__ __launch_bounds__(256) void state_combine(const float* __restrict__ P,
                                                     const float* __restrict__ state,
                                                     const float* __restrict__ A,
                                                     float* __restrict__ out_state) {
  int idx = blockIdx.x * 256 + threadIdx.x;
  int h = idx >> 14;
  int de = idx & 16383;
  float B = A[(size_t)h * SQLEN + SQLEN - 1];
  float s = __expf(B) * state[idx];
#pragma unroll
  for (int c = 0; c < 8; c++) s += P[(size_t)(h * 8 + c) * 16384 + de];
  out_state[idx] = s;
}

extern "C" void kernel_launch(void* const* d_in, const int* in_sizes, int n_in,
                              void* d_out, int out_size, void* d_ws, size_t ws_size,
                              hipStream_t stream) {
  const float* x = (const float*)d_in[0];
  const float* state = (const float*)d_in[1];
  const float* W_qkv = (const float*)d_in[2];
  const float* W_alpha = (const float*)d_in[3];
  const float* b_alpha = (const float*)d_in[4];
  const float* alpha_base = (const float*)d_in[5];
  const float* gn_w = (const float*)d_in[6];
  const float* gn_b = (const float*)d_in[7];
  const float* W_out = (const float*)d_in[8];
  const float* W_gate = (const float*)d_in[9];
  const int* offset = (const int*)d_in[10];

  float* ws = (float*)d_ws;
  // fp32 regions (float offsets):
  float* P   = ws;                    // overlay on dead xb after qkv gemm
  float* rn  = ws + 29360128;
  float* araw = ws + 33554432;
  float* Acum = ws + 33587200;

  // bf16 overlays (ushort):
  unsigned short* xb     = (unsigned short*)(ws + 0);        // [0, 2097152) fl
  unsigned short* Wqkvb  = (unsigned short*)(ws + 4194304);  // [4194304, 10485760) fl
  unsigned short* qb     = (unsigned short*)(ws + 12582912);
  unsigned short* kb     = (unsigned short*)(ws + 14680064);
  unsigned short* vb     = (unsigned short*)(ws + 16777216);
  unsigned short* kT_s   = (unsigned short*)(ws + 18874368);
  unsigned short* vT_b   = (unsigned short*)(ws + 20971520);
  unsigned short* stT_b  = (unsigned short*)(ws + 23068672);
  unsigned short* rnb    = (unsigned short*)(ws + 25165824);
  // phase 2 overlays (written after their underlying readers finish)
  unsigned short* Wgateb = (unsigned short*)(ws + 14680064); // over kb
  unsigned short* Woutb  = (unsigned short*)(ws + 16777216); // over vb
  unsigned short* Hb     = (unsigned short*)(ws + 18874368); // over kT_s

  float* out = (float*)d_out;
  float* out_state = out + 4194304;

  dim3 blk(256);
  f2b_kernel<<<dim3(4096), blk, 0, stream>>>((const float4*)x, (ushort4*)xb);
  f2bperm_kernel<<<dim3(12288), blk, 0, stream>>>(W_qkv, Wqkvb);
  alpha_kernel<<<dim3(512), blk, 0, stream>>>(x, W_alpha, b_alpha, alpha_base, araw);
  cumsum_kernel<<<dim3(16), blk, 0, stream>>>(araw, Acum);

  gemm_qkv_xpos<<<dim3(48, 16), blk, 0, stream>>>(xb, Wqkvb, araw, offset, qb, kb, vb);

  transpose_kv_kernel<<<dim3(32, 2, 32), blk, 0, stream>>>(kb, vb, Acum, kT_s, vT_b);
  transpose_state_kernel<<<dim3(2, 2, 16), blk, 0, stream>>>(state, stT_b);

  retention_mfma<<<dim3(16, 32), blk, 0, stream>>>(qb, kb, vT_b, stT_b, Acum,
                                                   gn_w, gn_b, rn, rnb);
  state_gemm<<<dim3(8, 16), blk, 0, stream>>>(kT_s, vT_b, P);
  state_combine<<<dim3(1024), blk, 0, stream>>>(P, state, Acum, out_state);

  f2b2_kernel<<<dim3(8192), blk, 0, stream>>>((const float4*)W_gate, (ushort4*)Wgateb,
                                              (const float4*)W_out, (ushort4*)Woutb, 4096);
  gemm_swish_nt<<<dim3(16, 16), blk, 0, stream>>>(rnb, Wgateb, rn, Hb, 2048, 2048, 2048);
  gemm_bf16_nt<<<dim3(16, 16), blk, 0, stream>>>(Hb, Woutb, out, 2048, 2048, 2048);
}